// Round 2
// baseline (8429.459 us; speedup 1.0000x reference)
//
#include <hip/hip_runtime.h>
#include <math.h>

#define DD 128
#define DT 16
#define NR 16
#define NS 16

__device__ __forceinline__ float ssilu(float x) {
    // silu(x) / 0.6
    return (x / (1.0f + __expf(-x))) * (1.0f / 0.6f);
}

__device__ __forceinline__ void load16(const float* __restrict__ p, float v[16]) {
    float4 a = *(const float4*)(p);
    float4 b = *(const float4*)(p + 4);
    float4 c = *(const float4*)(p + 8);
    float4 d = *(const float4*)(p + 12);
    v[0]=a.x; v[1]=a.y; v[2]=a.z; v[3]=a.w;
    v[4]=b.x; v[5]=b.y; v[6]=b.z; v[7]=b.w;
    v[8]=c.x; v[9]=c.y; v[10]=c.z; v[11]=c.w;
    v[12]=d.x; v[13]=d.y; v[14]=d.z; v[15]=d.w;
}

// ---------------------------------------------------------------------------
// K1: x_down[E][16] = (ssilu(m @ W_ba) * (rbf @ W_rbf)) @ W_down
// Tile: 128 edges x 128 cols, K=128. 256 threads, 8x8 micro-tile.
// LDS: 152 KB -> 1 block/CU.
// ---------------------------------------------------------------------------
__global__ __launch_bounds__(256) void k1_edge_pre(
    const float* __restrict__ m, const float* __restrict__ rbf,
    const float* __restrict__ W_ba, const float* __restrict__ W_rbf,
    const float* __restrict__ W_down, float* __restrict__ x_down, int E)
{
    __shared__ float rbf_s[128 * NR];   // 8KB
    __shared__ float wr_s[NR * DD];     // 8KB  W_rbf[q][j]
    __shared__ float wdT_s[DT * DD];    // 8KB  W_down^T: [d][j]
    __shared__ float mT_s[DD * 128];    // 64KB m^T: [k][e]
    __shared__ float w_s[DD * DD];      // 64KB W_ba[k][j]

    const int tid = threadIdx.x;
    const int e0 = blockIdx.x * 128;

    // stage W_ba (4096 float4)
    {
        const float4* src = (const float4*)W_ba;
        float4* dst = (float4*)w_s;
        #pragma unroll
        for (int i = 0; i < 16; ++i) dst[tid + 256 * i] = src[tid + 256 * i];
    }
    // stage W_rbf (512 float4)
    {
        const float4* src = (const float4*)W_rbf;
        float4* dst = (float4*)wr_s;
        dst[tid] = src[tid];
        dst[tid + 256] = src[tid + 256];
    }
    // stage W_down transposed: wdT_s[d*128 + j] = W_down[j*16 + d]
    {
        int j = tid >> 1;
        int dbase = (tid & 1) * 8;
        #pragma unroll
        for (int i = 0; i < 8; ++i)
            wdT_s[(dbase + i) * DD + j] = W_down[j * DT + dbase + i];
    }
    // stage m tile transposed + rbf tile (2 threads per edge row)
    {
        int e = tid >> 1;
        int half = tid & 1;
        int ge = e0 + e;
        bool ok = ge < E;
        #pragma unroll
        for (int i = 0; i < 16; ++i) {
            int k4 = half * 64 + i * 4;
            float4 v = ok ? *(const float4*)(m + (size_t)ge * DD + k4)
                          : make_float4(0.f, 0.f, 0.f, 0.f);
            mT_s[(k4 + 0) * 128 + e] = v.x;
            mT_s[(k4 + 1) * 128 + e] = v.y;
            mT_s[(k4 + 2) * 128 + e] = v.z;
            mT_s[(k4 + 3) * 128 + e] = v.w;
        }
        float4 r4 = ok ? *(const float4*)(rbf + (size_t)ge * NR + half * 8)
                       : make_float4(0.f, 0.f, 0.f, 0.f);
        float4 r5 = ok ? *(const float4*)(rbf + (size_t)ge * NR + half * 8 + 4)
                       : make_float4(0.f, 0.f, 0.f, 0.f);
        *(float4*)&rbf_s[e * NR + half * 8] = r4;
        *(float4*)&rbf_s[e * NR + half * 8 + 4] = r5;
    }
    __syncthreads();

    const int ty = tid >> 4;   // row group (8 edges)
    const int tx = tid & 15;   // col group (8 cols)
    const int row0 = ty * 8;
    const int col0 = tx * 8;

    float acc[8][8];
    #pragma unroll
    for (int r = 0; r < 8; ++r)
        #pragma unroll
        for (int c = 0; c < 8; ++c) acc[r][c] = 0.f;

    #pragma unroll 4
    for (int k = 0; k < DD; ++k) {
        float4 a0 = *(const float4*)&mT_s[k * 128 + row0];
        float4 a1 = *(const float4*)&mT_s[k * 128 + row0 + 4];
        float4 b0 = *(const float4*)&w_s[k * DD + col0];
        float4 b1 = *(const float4*)&w_s[k * DD + col0 + 4];
        float a[8] = {a0.x,a0.y,a0.z,a0.w,a1.x,a1.y,a1.z,a1.w};
        float b[8] = {b0.x,b0.y,b0.z,b0.w,b1.x,b1.y,b1.z,b1.w};
        #pragma unroll
        for (int r = 0; r < 8; ++r)
            #pragma unroll
            for (int c = 0; c < 8; ++c) acc[r][c] += a[r] * b[c];
    }

    // epilogue: ssilu * (rbf@W_rbf), then down-project 128->16 and
    // reduce-scatter the 16 partials across the 16 tx lanes (d = tx).
    #pragma unroll 1
    for (int r = 0; r < 8; ++r) {
        int erow = row0 + r;
        float rv[16];
        #pragma unroll
        for (int q = 0; q < NR; ++q) rv[q] = rbf_s[erow * NR + q];
        float pd[16];
        #pragma unroll
        for (int d = 0; d < 16; ++d) pd[d] = 0.f;
        #pragma unroll
        for (int c = 0; c < 8; ++c) {
            int col = col0 + c;
            float rw = 0.f;
            #pragma unroll
            for (int q = 0; q < NR; ++q) rw += rv[q] * wr_s[q * DD + col];
            float x = ssilu(acc[r][c]) * rw;
            #pragma unroll
            for (int d = 0; d < 16; ++d) pd[d] += x * wdT_s[d * DD + col];
        }
        // 4-step butterfly reduce-scatter over lanes tx=0..15
        float t8[8], t4[4], t2[2], res;
        {
            bool up = (tx & 8) != 0;
            #pragma unroll
            for (int i = 0; i < 8; ++i) {
                float send = up ? pd[i] : pd[8 + i];
                float keep = up ? pd[8 + i] : pd[i];
                t8[i] = keep + __shfl_xor(send, 8, 64);
            }
        }
        {
            bool up = (tx & 4) != 0;
            #pragma unroll
            for (int i = 0; i < 4; ++i) {
                float send = up ? t8[i] : t8[4 + i];
                float keep = up ? t8[4 + i] : t8[i];
                t4[i] = keep + __shfl_xor(send, 4, 64);
            }
        }
        {
            bool up = (tx & 2) != 0;
            #pragma unroll
            for (int i = 0; i < 2; ++i) {
                float send = up ? t4[i] : t4[2 + i];
                float keep = up ? t4[2 + i] : t4[i];
                t2[i] = keep + __shfl_xor(send, 2, 64);
            }
        }
        {
            bool up = (tx & 1) != 0;
            float send = up ? t2[0] : t2[1];
            float keep = up ? t2[1] : t2[0];
            res = keep + __shfl_xor(send, 1, 64);
        }
        int ge = e0 + erow;
        if (ge < E) x_down[(size_t)ge * DT + tx] = res;
    }
}

// ---------------------------------------------------------------------------
// K2: x_e[ca] += x_down[ba] * (cbf @ W_cbf)   (one thread per triplet)
// ---------------------------------------------------------------------------
__global__ __launch_bounds__(256) void k2_triplet(
    const float* __restrict__ cbf, const int* __restrict__ id3_ba,
    const int* __restrict__ id3_ca, const float* __restrict__ W_cbf,
    const float* __restrict__ x_down, float* __restrict__ x_e, int T)
{
    __shared__ float wc_s[NS * DT]; // 1KB
    if (threadIdx.x < 64)
        ((float4*)wc_s)[threadIdx.x] = ((const float4*)W_cbf)[threadIdx.x];
    __syncthreads();

    int t = blockIdx.x * 256 + threadIdx.x;
    if (t >= T) return;

    float cs[16];
    load16(cbf + (size_t)t * NS, cs);

    float cbv[16];
    #pragma unroll
    for (int j = 0; j < 16; ++j) cbv[j] = 0.f;
    #pragma unroll
    for (int s = 0; s < 16; ++s) {
        float bs = cs[s];
        float wrow[16];
        load16(&wc_s[s * DT], wrow);
        #pragma unroll
        for (int j = 0; j < 16; ++j) cbv[j] += bs * wrow[j];
    }

    int ba = id3_ba[t];
    int ca = id3_ca[t];
    float xv[16];
    load16(x_down + (size_t)ba * DT, xv);
    float* dst = x_e + (size_t)ca * DT;
    #pragma unroll
    for (int d = 0; d < 16; ++d) atomicAdd(dst + d, xv[d] * cbv[d]);
}

// ---------------------------------------------------------------------------
// K3: m_new = m + ssilu(x_e @ W_up);  h[idx_t] += m_new * (rbf @ W_rbf_atom)
// One wave per edge (grid-stride); lane handles 2 columns.
// ---------------------------------------------------------------------------
__global__ __launch_bounds__(256) void k3_edge_post(
    const float* __restrict__ m, const float* __restrict__ rbf,
    const float* __restrict__ x_e, const int* __restrict__ idx_t,
    const float* __restrict__ W_up, const float* __restrict__ W_ra,
    float* __restrict__ h, int E)
{
    __shared__ float wu_s[DT * DD]; // 8KB  W_up[d][j]
    __shared__ float wa_s[NR * DD]; // 8KB  W_rbf_atom[q][j]
    {
        const float4* s1 = (const float4*)W_up;  float4* d1 = (float4*)wu_s;
        const float4* s2 = (const float4*)W_ra;  float4* d2 = (float4*)wa_s;
        d1[threadIdx.x] = s1[threadIdx.x];
        d1[threadIdx.x + 256] = s1[threadIdx.x + 256];
        d2[threadIdx.x] = s2[threadIdx.x];
        d2[threadIdx.x + 256] = s2[threadIdx.x + 256];
    }
    __syncthreads();

    int lane = threadIdx.x & 63;
    int wv = (blockIdx.x * blockDim.x + threadIdx.x) >> 6;
    int nw = (gridDim.x * blockDim.x) >> 6;
    int j0 = lane * 2;

    for (int e = wv; e < E; e += nw) {
        float xv[16], rv[16];
        load16(x_e + (size_t)e * DT, xv);
        load16(rbf + (size_t)e * NR, rv);
        float2 mm = *(const float2*)(m + (size_t)e * DD + j0);

        float u0 = 0.f, u1 = 0.f, a0 = 0.f, a1 = 0.f;
        #pragma unroll
        for (int d = 0; d < 16; ++d) {
            float2 w = *(const float2*)&wu_s[d * DD + j0];
            u0 += xv[d] * w.x; u1 += xv[d] * w.y;
        }
        #pragma unroll
        for (int q = 0; q < 16; ++q) {
            float2 w = *(const float2*)&wa_s[q * DD + j0];
            a0 += rv[q] * w.x; a1 += rv[q] * w.y;
        }
        float v0 = (mm.x + ssilu(u0)) * a0;
        float v1 = (mm.y + ssilu(u1)) * a1;
        int at = idx_t[e];
        atomicAdd(&h[(size_t)at * DD + j0], v0);
        atomicAdd(&h[(size_t)at * DD + j0 + 1], v1);
    }
}

// ---------------------------------------------------------------------------
// K4: out = ssilu(h @ W_atom), in-place on d_out (h rows staged to LDS first).
// 32 atoms per block, 128 threads (thread = output column).
// ---------------------------------------------------------------------------
__global__ __launch_bounds__(128) void k4_atom(
    const float* __restrict__ W_atom, float* __restrict__ h_out, int Nat)
{
    __shared__ float w_s[DD * DD];  // 64KB
    __shared__ float h_s[32 * DD];  // 16KB
    int tid = threadIdx.x;
    {
        const float4* src = (const float4*)W_atom;
        float4* dst = (float4*)w_s;
        #pragma unroll
        for (int i = 0; i < 32; ++i) dst[tid + 128 * i] = src[tid + 128 * i];
    }
    int a0 = blockIdx.x * 32;
    {
        int r = tid >> 2, seg = tid & 3;
        int ga = a0 + r;
        #pragma unroll
        for (int i = 0; i < 8; ++i) {
            float4 v = (ga < Nat)
                ? *(const float4*)(h_out + (size_t)ga * DD + seg * 32 + i * 4)
                : make_float4(0.f, 0.f, 0.f, 0.f);
            *(float4*)&h_s[r * DD + seg * 32 + i * 4] = v;
        }
    }
    __syncthreads();

    float acc[32];
    #pragma unroll
    for (int r = 0; r < 32; ++r) acc[r] = 0.f;
    #pragma unroll 4
    for (int k = 0; k < DD; ++k) {
        float w = w_s[k * DD + tid];
        #pragma unroll
        for (int r = 0; r < 32; ++r) acc[r] += h_s[r * DD + k] * w;
    }
    #pragma unroll
    for (int r = 0; r < 32; ++r) {
        int ga = a0 + r;
        if (ga < Nat) h_out[(size_t)ga * DD + tid] = ssilu(acc[r]);
    }
}

// ---------------------------------------------------------------------------
extern "C" void kernel_launch(void* const* d_in, const int* in_sizes, int n_in,
                              void* d_out, int out_size, void* d_ws, size_t ws_size,
                              hipStream_t stream) {
    const float* m      = (const float*)d_in[0];
    const float* rbf    = (const float*)d_in[1];
    const float* cbf    = (const float*)d_in[2];
    const int*   id3_ba = (const int*)d_in[3];
    const int*   id3_ca = (const int*)d_in[4];
    const int*   idx_t  = (const int*)d_in[5];
    const float* W_ba   = (const float*)d_in[6];
    const float* W_rbf  = (const float*)d_in[7];
    const float* W_down = (const float*)d_in[8];
    const float* W_cbf  = (const float*)d_in[9];
    const float* W_up   = (const float*)d_in[10];
    const float* W_ra   = (const float*)d_in[11];
    const float* W_atom = (const float*)d_in[12];

    const int E   = in_sizes[0] / DD;
    const int T   = in_sizes[2] / NS;
    const int Nat = out_size / DD;

    float* x_down = (float*)d_ws;                       // E*16 f32
    float* x_e    = x_down + (size_t)E * DT;            // E*16 f32
    float* h      = (float*)d_out;                      // Nat*128 f32 (in d_out)

    hipMemsetAsync(x_e, 0, (size_t)E * DT * sizeof(float), stream);
    hipMemsetAsync(d_out, 0, (size_t)out_size * sizeof(float), stream);

    k1_edge_pre<<<(E + 127) / 128, 256, 0, stream>>>(
        m, rbf, W_ba, W_rbf, W_down, x_down, E);
    k2_triplet<<<(T + 255) / 256, 256, 0, stream>>>(
        cbf, id3_ba, id3_ca, W_cbf, x_down, x_e, T);
    k3_edge_post<<<2048, 256, 0, stream>>>(
        m, rbf, x_e, idx_t, W_up, W_ra, h, E);
    k4_atom<<<(Nat + 31) / 32, 128, 0, stream>>>(W_atom, h, Nat);
}